// Round 4
// baseline (352.056 us; speedup 1.0000x reference)
//
#include <hip/hip_runtime.h>
#include <stdint.h>
#include <math.h>

#define BATCH 8
#define NPB   4194304u          // 2048*2048 elements per batch
#define BPB   256               // blocks per batch
#define EPB   16384u            // elements per block (NPB / BPB)

#if defined(__has_builtin)
#if __has_builtin(__builtin_amdgcn_ballot_w64)
#define HAS_BALLOT64 1
#endif
#endif

// Tiny workspace: per-batch accumulators + arrival counters (128 B total).
// Zeroed each call by a hipMemsetAsync node -> robust to ws poisoning.
struct Ws {
  double   Ssum[BATCH];    // 64 B
  uint32_t Csum[BATCH];    // 32 B
  uint32_t arrive[BATCH];  // 32 B
};

// draw-0 and draw-1 subkeys per batch, computed on host each call
struct Keys {
  uint32_t a0[BATCH], a1[BATCH];   // draw 0
  uint32_t b0[BATCH], b1[BATCH];   // draw 1 (forced-accept fallback)
};

// ---------------- threefry2x32 (bit-exact with JAX) ----------------
__host__ __device__ __forceinline__ uint32_t rotl_h(uint32_t x, int n) {
  return (x << n) | (x >> (32 - n));
}

#ifdef __HIP_DEVICE_COMPILE__
// single v_alignbit_b32: ((x:x) >> (32-n)) == rotl(x,n)
#define ROTL(x, n) __builtin_amdgcn_alignbit((x), (x), 32 - (n))
#else
#define ROTL(x, n) rotl_h((x), (n))
#endif

__host__ __device__ __forceinline__ void tf2x32(uint32_t k0, uint32_t k1,
                                                uint32_t x0, uint32_t x1,
                                                uint32_t& y0, uint32_t& y1) {
  uint32_t k2 = k0 ^ k1 ^ 0x1BD11BDAu;
  x0 += k0; x1 += k1;
#define R4A x0+=x1; x1=ROTL(x1,13); x1^=x0; x0+=x1; x1=ROTL(x1,15); x1^=x0; \
            x0+=x1; x1=ROTL(x1,26); x1^=x0; x0+=x1; x1=ROTL(x1, 6); x1^=x0;
#define R4B x0+=x1; x1=ROTL(x1,17); x1^=x0; x0+=x1; x1=ROTL(x1,29); x1^=x0; \
            x0+=x1; x1=ROTL(x1,16); x1^=x0; x0+=x1; x1=ROTL(x1,24); x1^=x0;
  R4A x0 += k1; x1 += k2 + 1u;
  R4B x0 += k2; x1 += k0 + 2u;
  R4A x0 += k0; x1 += k1 + 3u;
  R4B x0 += k1; x1 += k2 + 4u;
  R4A x0 += k2; x1 += k0 + 5u;
#undef R4A
#undef R4B
  y0 = x0; y1 = x1;
}

// partitionable-mode 32-bit sample for element j: y0 ^ y1 of tf(sub,(0,j))
__device__ __forceinline__ uint32_t tf_bits(uint32_t s0, uint32_t s1, uint32_t j) {
  uint32_t y0, y1;
  tf2x32(s0, s1, 0u, j, y0, y1);
  return y0 ^ y1;
}

// JAX uniform[0,1): bitcast((bits>>9)|0x3f800000) - 1.0
// (bits>>9)|0x3f800000 == alignbit(0x7F, bits, 9) : one VALU op
__device__ __forceinline__ float u01(uint32_t b) {
#ifdef __HIP_DEVICE_COMPILE__
  return __uint_as_float(__builtin_amdgcn_alignbit(0x7Fu, b, 9)) - 1.0f;
#else
  return __uint_as_float((b >> 9) | 0x3f800000u) - 1.0f;
#endif
}

// ---------------- fused: anchor's unrolled/pipelined main pass + last-block resolve ----
// Hot loop restored VERBATIM from the 240.9 us anchor (unrolled, sw-pipelined,
// plain cached float4 loads/stores: input stays L3-resident across bench
// iterations; NT hints measured -18 us in R3 -- reverted).
__global__ __launch_bounds__(256) void k_fused(const float* __restrict__ x,
                                               float* __restrict__ out,
                                               Ws* __restrict__ ws, Keys keys) {
  const int b = blockIdx.y;
  const uint32_t s0 = keys.a0[b], s1 = keys.a1[b];
  const uint32_t base = blockIdx.x * EPB + threadIdx.x * 4u;
  const float* __restrict__ pA = x + (size_t)b * NPB + base;
  float*       __restrict__ qA = out + (size_t)b * NPB + base;

  uint32_t c = 0;          // count: wave-uniform on ballot path
  float    sf = 0.0f;      // per-thread f32 partial sum (<=64 values in [0,1))

  // software pipeline: prefetch iteration 0
  float4 xa = *(const float4*)(pA);
  float4 xc = *(const float4*)(pA + 1024);
  uint32_t j = base;

#pragma unroll
  for (int it = 0; it < 8; ++it) {
    float4 na = xa, nc = xc;
    if (it < 7) {                       // prefetch next iteration's data
      na = *(const float4*)(pA + 2048);
      nc = *(const float4*)(pA + 3072);
    }
    float4 oa, oc;
#ifdef HAS_BALLOT64
#define CNT(p) c += (uint32_t)__builtin_popcountll(__builtin_amdgcn_ballot_w64(p))
#else
#define CNT(p) c += (uint32_t)(p)
#endif
#define DOPAIR(comp, off) {                                               \
      bool p0 = xa.comp > u01(tf_bits(s0, s1, j + off));                  \
      bool p1 = xc.comp > u01(tf_bits(s0, s1, j + off + 1024u));          \
      oa.comp = p0 ? 1.0f : 0.0f; oc.comp = p1 ? 1.0f : 0.0f;             \
      CNT(p0); CNT(p1); }
    DOPAIR(x, 0u) DOPAIR(y, 1u) DOPAIR(z, 2u) DOPAIR(w, 3u)
#undef DOPAIR
#undef CNT
    sf += ((xa.x + xa.y) + (xa.z + xa.w)) + ((xc.x + xc.y) + (xc.z + xc.w));
    *(float4*)(qA)        = oa;
    *(float4*)(qA + 1024) = oc;
    pA += 2048; qA += 2048; j += 2048u;
    xa = na; xc = nc;
  }

  // block-level reduce: sum in f64 across wave; count wave-uniform on ballot path
  double S = (double)sf;
  for (int off = 32; off > 0; off >>= 1) S += __shfl_down(S, off, 64);
#ifndef HAS_BALLOT64
  for (int off = 32; off > 0; off >>= 1) c += __shfl_down(c, off, 64);
#endif

  __shared__ double   sS[4];
  __shared__ uint32_t sC[4];
  __shared__ int      sLast, sAcc;
  const int lane = threadIdx.x & 63, wave = threadIdx.x >> 6;
  if (lane == 0) { sS[wave] = S; sC[wave] = c; }
  __syncthreads();
  if (threadIdx.x == 0) {
    double   Sb = (sS[0] + sS[1]) + (sS[2] + sS[3]);
    uint32_t Cb = (sC[0] + sC[1]) + (sC[2] + sC[3]);
    atomicAdd(&ws->Ssum[b], Sb);            // f64 atomic; order-noise ~1e-13 << 7.6e-4 margin
    atomicAdd(&ws->Csum[b], Cb);
    __threadfence();                        // release: out-stores + accumulators
    uint32_t old = atomicAdd(&ws->arrive[b], 1u);
    sLast = (old == BPB - 1u) ? 1 : 0;
  }
  __syncthreads();
  if (!sLast) return;

  // last block of batch b: decide accept/reject (all 2048 adds happened-before)
  if (threadIdx.x == 0) {
    __threadfence();                        // acquire
    double   St = ws->Ssum[b];
    uint32_t Ct = ws->Csum[b];
    float target = (float)(St / (double)NPB);
    float thr    = 1e-3f + 1e-5f * fabsf(target);
    float m      = (float)Ct * (1.0f / (float)NPB);
    sAcc = (fabsf(m - target) <= thr) ? 1 : 0;
  }
  __syncthreads();
  if (sAcc) return;

  // never-path (~4e-5 per batch; deterministic per input -- never taken for the
  // bench input): this block alone rewrites the whole batch with draw-1 subkey.
  {
    const uint32_t t0 = keys.b0[b], t1 = keys.b1[b];
    const float* __restrict__ xb = x + (size_t)b * NPB;
    float*       __restrict__ ob = out + (size_t)b * NPB;
#pragma unroll 1
    for (uint32_t jj = threadIdx.x * 4u; jj < NPB; jj += 1024u) {
      float4 v = *(const float4*)(xb + jj);
      float4 o;
      o.x = (v.x > u01(tf_bits(t0, t1, jj + 0u))) ? 1.0f : 0.0f;
      o.y = (v.y > u01(tf_bits(t0, t1, jj + 1u))) ? 1.0f : 0.0f;
      o.z = (v.z > u01(tf_bits(t0, t1, jj + 2u))) ? 1.0f : 0.0f;
      o.w = (v.w > u01(tf_bits(t0, t1, jj + 3u))) ? 1.0f : 0.0f;
      *(float4*)(ob + jj) = o;
    }
  }
}

extern "C" void kernel_launch(void* const* d_in, const int* in_sizes, int n_in,
                              void* d_out, int out_size, void* d_ws, size_t ws_size,
                              hipStream_t stream) {
  const float* x = (const float*)d_in[0];
  float* out = (float*)d_out;
  Ws* ws = (Ws*)d_ws;

  // Host-side key schedule (pure arithmetic — graph-capture safe, same every call).
  // keys[b] = tf((0,42),(0,b)) [fold-in split]; per draw: k' = tf(k,(0,0)), sub = tf(k,(0,1)).
  Keys keys;
  for (int b = 0; b < BATCH; ++b) {
    uint32_t k0, k1, n0, n1, s0, s1;
    tf2x32(0u, 42u, 0u, (uint32_t)b, k0, k1);
    tf2x32(k0, k1, 0u, 1u, s0, s1);      // draw-0 subkey
    keys.a0[b] = s0; keys.a1[b] = s1;
    tf2x32(k0, k1, 0u, 0u, n0, n1);      // advance key
    tf2x32(n0, n1, 0u, 1u, s0, s1);      // draw-1 subkey
    keys.b0[b] = s0; keys.b1[b] = s1;
  }

  // zero the 128 B accumulator block (stream-ordered: graph-capture safe)
  hipMemsetAsync(d_ws, 0, sizeof(Ws), stream);
  hipLaunchKernelGGL(k_fused, dim3(BPB, BATCH), dim3(256), 0, stream, x, out, ws, keys);
}

// Round 6
// 346.081 us; speedup vs baseline: 1.0173x; 1.0173x over previous
//
#include <hip/hip_runtime.h>
#include <stdint.h>
#include <math.h>

#define BATCH 8
#define NPB   4194304u          // 2048*2048 elements per batch
#define BPB   256               // blocks per batch
#define EPB   16384u            // elements per block (NPB / BPB)

#if defined(__has_builtin)
#if __has_builtin(__builtin_amdgcn_ballot_w64)
#define HAS_BALLOT64 1
#endif
#endif

// Tiny workspace: per-batch accumulators + arrival counters (128 B total).
// Zeroed each call by a hipMemsetAsync node -> robust to ws poisoning.
struct Ws {
  double   Ssum[BATCH];    // 64 B
  uint32_t Csum[BATCH];    // 32 B
  uint32_t arrive[BATCH];  // 32 B
};

// draw-0 and draw-1 subkeys per batch, computed on host each call
struct Keys {
  uint32_t a0[BATCH], a1[BATCH];   // draw 0
  uint32_t b0[BATCH], b1[BATCH];   // draw 1 (forced-accept fallback)
};

// ---------------- threefry2x32 (bit-exact with JAX) ----------------
__host__ __device__ __forceinline__ uint32_t rotl_h(uint32_t x, int n) {
  return (x << n) | (x >> (32 - n));
}

#ifdef __HIP_DEVICE_COMPILE__
// single v_alignbit_b32: ((x:x) >> (32-n)) == rotl(x,n)
#define ROTL(x, n) __builtin_amdgcn_alignbit((x), (x), 32 - (n))
#else
#define ROTL(x, n) rotl_h((x), (n))
#endif

__host__ __device__ __forceinline__ void tf2x32(uint32_t k0, uint32_t k1,
                                                uint32_t x0, uint32_t x1,
                                                uint32_t& y0, uint32_t& y1) {
  uint32_t k2 = k0 ^ k1 ^ 0x1BD11BDAu;
  x0 += k0; x1 += k1;
#define R4A x0+=x1; x1=ROTL(x1,13); x1^=x0; x0+=x1; x1=ROTL(x1,15); x1^=x0; \
            x0+=x1; x1=ROTL(x1,26); x1^=x0; x0+=x1; x1=ROTL(x1, 6); x1^=x0;
#define R4B x0+=x1; x1=ROTL(x1,17); x1^=x0; x0+=x1; x1=ROTL(x1,29); x1^=x0; \
            x0+=x1; x1=ROTL(x1,16); x1^=x0; x0+=x1; x1=ROTL(x1,24); x1^=x0;
  R4A x0 += k1; x1 += k2 + 1u;
  R4B x0 += k2; x1 += k0 + 2u;
  R4A x0 += k0; x1 += k1 + 3u;
  R4B x0 += k1; x1 += k2 + 4u;
  R4A x0 += k2; x1 += k0 + 5u;
#undef R4A
#undef R4B
  y0 = x0; y1 = x1;
}

// partitionable-mode 32-bit sample for element j: y0 ^ y1 of tf(sub,(0,j))
__device__ __forceinline__ uint32_t tf_bits(uint32_t s0, uint32_t s1, uint32_t j) {
  uint32_t y0, y1;
  tf2x32(s0, s1, 0u, j, y0, y1);
  return y0 ^ y1;
}

// JAX uniform[0,1): bitcast((bits>>9)|0x3f800000) - 1.0
// (bits>>9)|0x3f800000 == alignbit(0x7F, bits, 9) : one VALU op
__device__ __forceinline__ float u01(uint32_t b) {
#ifdef __HIP_DEVICE_COMPILE__
  return __uint_as_float(__builtin_amdgcn_alignbit(0x7Fu, b, 9)) - 1.0f;
#else
  return __uint_as_float((b >> 9) | 0x3f800000u) - 1.0f;
#endif
}

// ---------------- fused: ROLLED main loop (R3: 92us, VGPR32, VALU85%) ----------------
// + prefetch-1 inside the rolled body (probe: latency- vs retire-bound)
// + last-block resolve (removes the second kernel launch).
// R4 measured the unrolled body at 199us / VALU 30% (L1I thrash) -- do not unroll.
__global__ __launch_bounds__(256) void k_fused(const float* __restrict__ x,
                                               float* __restrict__ out,
                                               Ws* __restrict__ ws, Keys keys) {
  const int b = blockIdx.y;
  const uint32_t s0 = keys.a0[b], s1 = keys.a1[b];
  const uint32_t base = blockIdx.x * EPB + threadIdx.x * 4u;
  const float* __restrict__ pA = x + (size_t)b * NPB + base;
  float*       __restrict__ qA = out + (size_t)b * NPB + base;

  uint32_t c = 0;          // count: wave-uniform on ballot path
  float    sf = 0.0f;      // per-thread f32 partial sum (<=64 values in [0,1))
  uint32_t j = base;

  // prefetch iteration 0
  float4 xa = *(const float4*)(pA);
  float4 xc = *(const float4*)(pA + 1024);

#pragma unroll 1
  for (int it = 0; it < 8; ++it) {
    float4 na = xa, nc = xc;
    if (it < 7) {                       // prefetch next iteration (guard: last iter OOB)
      na = *(const float4*)(pA + 2048);
      nc = *(const float4*)(pA + 3072);
    }
    float4 oa, oc;
#ifdef HAS_BALLOT64
#define CNT(p) c += (uint32_t)__builtin_popcountll(__builtin_amdgcn_ballot_w64(p))
#else
#define CNT(p) c += (uint32_t)(p)
#endif
#define DOPAIR(comp, off) {                                               \
      bool p0 = xa.comp > u01(tf_bits(s0, s1, j + off));                  \
      bool p1 = xc.comp > u01(tf_bits(s0, s1, j + off + 1024u));          \
      oa.comp = p0 ? 1.0f : 0.0f; oc.comp = p1 ? 1.0f : 0.0f;             \
      CNT(p0); CNT(p1); }
    DOPAIR(x, 0u) DOPAIR(y, 1u) DOPAIR(z, 2u) DOPAIR(w, 3u)
#undef DOPAIR
#undef CNT
    sf += ((xa.x + xa.y) + (xa.z + xa.w)) + ((xc.x + xc.y) + (xc.z + xc.w));
    *(float4*)(qA)        = oa;
    *(float4*)(qA + 1024) = oc;
    pA += 2048; qA += 2048; j += 2048u;
    xa = na; xc = nc;
  }

  // block-level reduce: sum in f64 across wave; count wave-uniform on ballot path
  double S = (double)sf;
  for (int off = 32; off > 0; off >>= 1) S += __shfl_down(S, off, 64);
#ifndef HAS_BALLOT64
  for (int off = 32; off > 0; off >>= 1) c += __shfl_down(c, off, 64);
#endif

  __shared__ double   sS[4];
  __shared__ uint32_t sC[4];
  __shared__ int      sLast, sAcc;
  const int lane = threadIdx.x & 63, wave = threadIdx.x >> 6;
  if (lane == 0) { sS[wave] = S; sC[wave] = c; }
  __syncthreads();
  if (threadIdx.x == 0) {
    double   Sb = (sS[0] + sS[1]) + (sS[2] + sS[3]);
    uint32_t Cb = (sC[0] + sC[1]) + (sC[2] + sC[3]);
    atomicAdd(&ws->Ssum[b], Sb);            // f64 atomic; order-noise ~1e-13 << 7.6e-4 margin
    atomicAdd(&ws->Csum[b], Cb);
    __threadfence();                        // release: out-stores + accumulators
    uint32_t old = atomicAdd(&ws->arrive[b], 1u);
    sLast = (old == BPB - 1u) ? 1 : 0;
  }
  __syncthreads();
  if (!sLast) return;

  // last block of batch b: decide accept/reject (all 2048 adds happened-before)
  if (threadIdx.x == 0) {
    __threadfence();                        // acquire
    double   St = ws->Ssum[b];
    uint32_t Ct = ws->Csum[b];
    float target = (float)(St / (double)NPB);
    float thr    = 1e-3f + 1e-5f * fabsf(target);
    float m      = (float)Ct * (1.0f / (float)NPB);
    sAcc = (fabsf(m - target) <= thr) ? 1 : 0;
  }
  __syncthreads();
  if (sAcc) return;

  // never-path (deterministic per input; not taken for the bench input):
  // this block alone rewrites the whole batch with the draw-1 subkey.
  {
    const uint32_t t0 = keys.b0[b], t1 = keys.b1[b];
    const float* __restrict__ xb = x + (size_t)b * NPB;
    float*       __restrict__ ob = out + (size_t)b * NPB;
#pragma unroll 1
    for (uint32_t jj = threadIdx.x * 4u; jj < NPB; jj += 1024u) {
      float4 v = *(const float4*)(xb + jj);
      float4 o;
      o.x = (v.x > u01(tf_bits(t0, t1, jj + 0u))) ? 1.0f : 0.0f;
      o.y = (v.y > u01(tf_bits(t0, t1, jj + 1u))) ? 1.0f : 0.0f;
      o.z = (v.z > u01(tf_bits(t0, t1, jj + 2u))) ? 1.0f : 0.0f;
      o.w = (v.w > u01(tf_bits(t0, t1, jj + 3u))) ? 1.0f : 0.0f;
      *(float4*)(ob + jj) = o;
    }
  }
}

extern "C" void kernel_launch(void* const* d_in, const int* in_sizes, int n_in,
                              void* d_out, int out_size, void* d_ws, size_t ws_size,
                              hipStream_t stream) {
  const float* x = (const float*)d_in[0];
  float* out = (float*)d_out;
  Ws* ws = (Ws*)d_ws;

  // Host-side key schedule (pure arithmetic — graph-capture safe, same every call).
  // keys[b] = tf((0,42),(0,b)) [fold-in split]; per draw: k' = tf(k,(0,0)), sub = tf(k,(0,1)).
  Keys keys;
  for (int b = 0; b < BATCH; ++b) {
    uint32_t k0, k1, n0, n1, s0, s1;
    tf2x32(0u, 42u, 0u, (uint32_t)b, k0, k1);
    tf2x32(k0, k1, 0u, 1u, s0, s1);      // draw-0 subkey
    keys.a0[b] = s0; keys.a1[b] = s1;
    tf2x32(k0, k1, 0u, 0u, n0, n1);      // advance key
    tf2x32(n0, n1, 0u, 1u, s0, s1);      // draw-1 subkey
    keys.b0[b] = s0; keys.b1[b] = s1;
  }

  // zero the 128 B accumulator block (stream-ordered: graph-capture safe)
  hipMemsetAsync(d_ws, 0, sizeof(Ws), stream);
  hipLaunchKernelGGL(k_fused, dim3(BPB, BATCH), dim3(256), 0, stream, x, out, ws, keys);
}

// Round 7
// 239.367 us; speedup vs baseline: 1.4708x; 1.4458x over previous
//
#include <hip/hip_runtime.h>
#include <stdint.h>
#include <math.h>

#define BATCH 8
#define NPB   4194304u          // 2048*2048 elements per batch
#define BPB   256               // blocks per batch
#define EPB   16384u            // elements per block (NPB / BPB)

#if defined(__has_builtin)
#if __has_builtin(__builtin_amdgcn_ballot_w64)
#define HAS_BALLOT64 1
#endif
#endif

// native clang ext-vector: accepted by __builtin_nontemporal_{load,store},
// layout-identical to HIP float4 (16B)
typedef float f32x4 __attribute__((ext_vector_type(4)));

// Per-(batch,block) partials. k_main writes EVERY entry each call before
// k_resolve reads them -> immune to workspace poisoning, no memset needed.
struct Ws {
  double   psum[BATCH][BPB];
  uint32_t pcnt[BATCH][BPB];
};

// draw-0 and draw-1 subkeys per batch, computed on host each call
struct Keys {
  uint32_t a0[BATCH], a1[BATCH];   // draw 0
  uint32_t b0[BATCH], b1[BATCH];   // draw 1 (forced-accept fallback)
};

// ---------------- threefry2x32 (bit-exact with JAX) ----------------
__host__ __device__ __forceinline__ uint32_t rotl_h(uint32_t x, int n) {
  return (x << n) | (x >> (32 - n));
}

#ifdef __HIP_DEVICE_COMPILE__
// single v_alignbit_b32: ((x:x) >> (32-n)) == rotl(x,n)
#define ROTL(x, n) __builtin_amdgcn_alignbit((x), (x), 32 - (n))
#else
#define ROTL(x, n) rotl_h((x), (n))
#endif

__host__ __device__ __forceinline__ void tf2x32(uint32_t k0, uint32_t k1,
                                                uint32_t x0, uint32_t x1,
                                                uint32_t& y0, uint32_t& y1) {
  uint32_t k2 = k0 ^ k1 ^ 0x1BD11BDAu;
  x0 += k0; x1 += k1;
#define R4A x0+=x1; x1=ROTL(x1,13); x1^=x0; x0+=x1; x1=ROTL(x1,15); x1^=x0; \
            x0+=x1; x1=ROTL(x1,26); x1^=x0; x0+=x1; x1=ROTL(x1, 6); x1^=x0;
#define R4B x0+=x1; x1=ROTL(x1,17); x1^=x0; x0+=x1; x1=ROTL(x1,29); x1^=x0; \
            x0+=x1; x1=ROTL(x1,16); x1^=x0; x0+=x1; x1=ROTL(x1,24); x1^=x0;
  R4A x0 += k1; x1 += k2 + 1u;
  R4B x0 += k2; x1 += k0 + 2u;
  R4A x0 += k0; x1 += k1 + 3u;
  R4B x0 += k1; x1 += k2 + 4u;
  R4A x0 += k2; x1 += k0 + 5u;
#undef R4A
#undef R4B
  y0 = x0; y1 = x1;
}

// partitionable-mode 32-bit sample for element j: y0 ^ y1 of tf(sub,(0,j))
__device__ __forceinline__ uint32_t tf_bits(uint32_t s0, uint32_t s1, uint32_t j) {
  uint32_t y0, y1;
  tf2x32(s0, s1, 0u, j, y0, y1);
  return y0 ^ y1;
}

// JAX uniform[0,1): bitcast((bits>>9)|0x3f800000) - 1.0
// (bits>>9)|0x3f800000 == alignbit(0x7F, bits, 9) : one VALU op
__device__ __forceinline__ float u01(uint32_t b) {
#ifdef __HIP_DEVICE_COMPILE__
  return __uint_as_float(__builtin_amdgcn_alignbit(0x7Fu, b, 9)) - 1.0f;
#else
  return __uint_as_float((b >> 9) | 0x3f800000u) - 1.0f;
#endif
}

// ---------------- main pass: stats for draw 0 + optimistic mask ----------------
// R3 baseline (this kernel, unroll 1): 92us, VGPR32, VALU(reported)85%.
// Real VALU busy ~42% (gfx94x formula assumes SIMD-16; gfx950 is SIMD-32) ->
// ~60% idle. Theory: rolled body reuses oa/oc/xa/xc every iteration, forcing
// s_waitcnt on the previous NT-store's HBM ack (~600-900cy) before each
// iteration's compute. unroll 2 gives two register sets -> breaks the
// store-ack/reg-reuse serialization. Body ~9KB, well inside 32KB L1I.
// DO NOT fuse the resolve here: R4/R6 measured the per-block __threadfence
// tail at +107us (199 vs 92) from device-scope L2 writeback churn.
__global__ __launch_bounds__(256) void k_main(const float* __restrict__ x,
                                              float* __restrict__ out,
                                              Ws* __restrict__ ws, Keys keys) {
  const int b = blockIdx.y;
  const uint32_t s0 = keys.a0[b], s1 = keys.a1[b];
  const uint32_t base = blockIdx.x * EPB + threadIdx.x * 4u;
  const float* __restrict__ pA = x + (size_t)b * NPB + base;
  float*       __restrict__ qA = out + (size_t)b * NPB + base;

  uint32_t c = 0;          // count: wave-uniform on ballot path
  float    sf = 0.0f;      // per-thread f32 partial sum (<=64 values in [0,1))
  uint32_t j = base;

#pragma unroll 2
  for (int it = 0; it < 8; ++it) {
    f32x4 xa = __builtin_nontemporal_load((const f32x4*)(pA));
    f32x4 xc = __builtin_nontemporal_load((const f32x4*)(pA + 1024));
    f32x4 oa, oc;
#ifdef HAS_BALLOT64
#define CNT(p) c += (uint32_t)__builtin_popcountll(__builtin_amdgcn_ballot_w64(p))
#else
#define CNT(p) c += (uint32_t)(p)
#endif
#define DOPAIR(k, off) {                                                  \
      bool p0 = xa[k] > u01(tf_bits(s0, s1, j + off));                    \
      bool p1 = xc[k] > u01(tf_bits(s0, s1, j + off + 1024u));            \
      oa[k] = p0 ? 1.0f : 0.0f; oc[k] = p1 ? 1.0f : 0.0f;                 \
      CNT(p0); CNT(p1); }
    DOPAIR(0, 0u) DOPAIR(1, 1u) DOPAIR(2, 2u) DOPAIR(3, 3u)
#undef DOPAIR
#undef CNT
    sf += ((xa[0] + xa[1]) + (xa[2] + xa[3])) + ((xc[0] + xc[1]) + (xc[2] + xc[3]));
    __builtin_nontemporal_store(oa, (f32x4*)(qA));
    __builtin_nontemporal_store(oc, (f32x4*)(qA + 1024));
    pA += 2048; qA += 2048; j += 2048u;
  }

  // reduce: sum across wave in f64; count is wave-uniform on the ballot path
  double S = (double)sf;
  for (int off = 32; off > 0; off >>= 1) S += __shfl_down(S, off, 64);
#ifndef HAS_BALLOT64
  for (int off = 32; off > 0; off >>= 1) c += __shfl_down(c, off, 64);
#endif

  __shared__ double   sS[4];
  __shared__ uint32_t sC[4];
  const int lane = threadIdx.x & 63, wave = threadIdx.x >> 6;
  if (lane == 0) { sS[wave] = S; sC[wave] = c; }
  __syncthreads();
  if (threadIdx.x == 0) {
    ws->psum[b][blockIdx.x] = (sS[0] + sS[1]) + (sS[2] + sS[3]);
    ws->pcnt[b][blockIdx.x] = (sC[0] + sC[1]) + (sC[2] + sC[3]);
  }
}

// ---------------- resolve: ONE block per batch decides; rare-path rewrite ----------------
// 8 blocks total (was 2048): reduce 256 partials, decide, and on the never-
// path (deterministic per input; not taken for the bench input) this single
// block rewrites the whole batch with the draw-1 subkey.
__global__ __launch_bounds__(256) void k_resolve(const float* __restrict__ x,
                                                 float* __restrict__ out,
                                                 Ws* __restrict__ ws, Keys keys) {
  const int b = blockIdx.y;

  double   S = ws->psum[b][threadIdx.x];
  uint32_t c = ws->pcnt[b][threadIdx.x];
  for (int off = 32; off > 0; off >>= 1) {
    c += __shfl_down(c, off, 64);
    S += __shfl_down(S, off, 64);
  }
  __shared__ double   sS[4];
  __shared__ uint32_t sC[4];
  __shared__ int      sAccept;
  const int lane = threadIdx.x & 63, wave = threadIdx.x >> 6;
  if (lane == 0) { sS[wave] = S; sC[wave] = c; }
  __syncthreads();
  if (threadIdx.x == 0) {
    double St = (sS[0] + sS[1]) + (sS[2] + sS[3]);
    uint32_t Ct = (sC[0] + sC[1]) + (sC[2] + sC[3]);
    float target = (float)(St / (double)NPB);
    float thr    = 1e-3f + 1e-5f * fabsf(target);
    float m      = (float)Ct * (1.0f / (float)NPB);
    sAccept = (fabsf(m - target) <= thr) ? 1 : 0;
  }
  __syncthreads();
  if (sAccept) return;

  // never-path: rewrite whole batch with draw-1 subkey (single block; slow but unreachable)
  const uint32_t t0 = keys.b0[b], t1 = keys.b1[b];
  const float* __restrict__ xb = x + (size_t)b * NPB;
  float*       __restrict__ ob = out + (size_t)b * NPB;
#pragma unroll 1
  for (uint32_t jj = threadIdx.x * 4u; jj < NPB; jj += 1024u) {
    float4 v = *(const float4*)(xb + jj);
    float4 o;
    o.x = (v.x > u01(tf_bits(t0, t1, jj + 0u))) ? 1.0f : 0.0f;
    o.y = (v.y > u01(tf_bits(t0, t1, jj + 1u))) ? 1.0f : 0.0f;
    o.z = (v.z > u01(tf_bits(t0, t1, jj + 2u))) ? 1.0f : 0.0f;
    o.w = (v.w > u01(tf_bits(t0, t1, jj + 3u))) ? 1.0f : 0.0f;
    *(float4*)(ob + jj) = o;
  }
}

extern "C" void kernel_launch(void* const* d_in, const int* in_sizes, int n_in,
                              void* d_out, int out_size, void* d_ws, size_t ws_size,
                              hipStream_t stream) {
  const float* x = (const float*)d_in[0];
  float* out = (float*)d_out;
  Ws* ws = (Ws*)d_ws;

  // Host-side key schedule (pure arithmetic — graph-capture safe, same every call).
  // keys[b] = tf((0,42),(0,b)) [fold-in split]; per draw: k' = tf(k,(0,0)), sub = tf(k,(0,1)).
  Keys keys;
  for (int b = 0; b < BATCH; ++b) {
    uint32_t k0, k1, n0, n1, s0, s1;
    tf2x32(0u, 42u, 0u, (uint32_t)b, k0, k1);
    tf2x32(k0, k1, 0u, 1u, s0, s1);      // draw-0 subkey
    keys.a0[b] = s0; keys.a1[b] = s1;
    tf2x32(k0, k1, 0u, 0u, n0, n1);      // advance key
    tf2x32(n0, n1, 0u, 1u, s0, s1);      // draw-1 subkey
    keys.b0[b] = s0; keys.b1[b] = s1;
  }

  hipLaunchKernelGGL(k_main,    dim3(BPB, BATCH), dim3(256), 0, stream, x, out, ws, keys);
  hipLaunchKernelGGL(k_resolve, dim3(1,   BATCH), dim3(256), 0, stream, x, out, ws, keys);
}